// Round 16
// baseline (209.743 us; speedup 1.0000x reference)
//
#include <hip/hip_runtime.h>
#include <hip/hip_bf16.h>
#include <cstdint>
#include <cstddef>

#define CC   96
#define BB   32
#define HHn  112
#define WWn  112
#define HWn  (HHn*WWn)        // 12544
#define NPIX (BB*HWn)         // 401408
#define EPSf 1e-5f

typedef __attribute__((ext_vector_type(8))) short bf16x8;
typedef __attribute__((ext_vector_type(4))) float f32x4;

__device__ inline unsigned short f2bf(float f) {      // RNE f32 -> bf16 (bit math)
  unsigned u = __float_as_uint(f);
  return (unsigned short)((u + 0x7FFFu + ((u >> 16) & 1u)) >> 16);
}
__device__ inline float bf2f(unsigned short h) {
  return __uint_as_float(((unsigned)h) << 16);
}
__device__ inline float bflo(unsigned u) { return __uint_as_float(u << 16); }
__device__ inline float bfhi(unsigned u) { return __uint_as_float(u & 0xffff0000u); }
__device__ inline unsigned pkbf(float a, float b) {   // v_cvt_pk_bf16_f32 (RNE)
  __hip_bfloat162 h = __float22bfloat162_rn(float2{a, b});
  return *reinterpret_cast<unsigned*>(&h);
}

// ---------------- w_mix f32[o][c] -> bf16[o][c] ----------------
__global__ __launch_bounds__(256) void k_prep(const float* __restrict__ w,
                                              unsigned short* __restrict__ wbf) {
  int i = blockIdx.x * 256 + threadIdx.x;
  if (i < CC * CC) wbf[i] = f2bf(w[i]);
}

// ---------------- depthwise 7x7 conv: bf16 LDS quarter-plane ----------------
// Block = quarter of one (b,c) plane (28 output rows), 128 threads (2 waves).
// 12288 small blocks -> ~16 blocks/CU at DIFFERENT pipeline phases (breaks the
// lockstep stall alignment of 8-wave blocks; r9-r14 plateau at ~100us was
// phase-synchronized stalls, not capacity). LDS 34 rows x 112 bf16 = 7.6 KB.
// Item (112 active): q=tid/28 (7-row chunk), s=tid%28 (4-col strip);
// per input row 3x ds_read_b64, unpack once to win[12], 7x7x4 fmaf.
__global__ __launch_bounds__(128, 8) void k_conv(const float* __restrict__ x,
                                                 const float* __restrict__ hk,
                                                 unsigned short* __restrict__ feat) {
  __shared__ unsigned short lpl[34 * WWn];   // 7,616 B

  int tid = threadIdx.x;
  int bid = blockIdx.x;                                     // 12288
  int plane = __builtin_amdgcn_readfirstlane(bid >> 2);     // (b*C+c)
  int quad  = __builtin_amdgcn_readfirstlane(bid & 3);
  int c = plane % CC;
  int r0 = quad * 28;                   // first output row of this quarter
  const float* xp = x + (long)plane * HWn;
  unsigned short* fp = feat + (long)plane * HWn;

  // ---- stage rows r0-3 .. r0+30 (34, row-clamped) f32 -> bf16: 952 float4 ----
#pragma unroll
  for (int it = 0; it < 8; ++it) {
    int idx = it * 128 + tid;
    if (idx < 952) {
      int rl = idx / 28;                // local row 0..33
      int c4 = idx % 28;
      int g = r0 - 3 + rl;
      int gc = g < 0 ? 0 : (g > HHn - 1 ? HHn - 1 : g);
      float4 v = *(const float4*)(xp + gc * WWn + c4 * 4);
      uint2 pk;
      pk.x = pkbf(v.x, v.y);
      pk.y = pkbf(v.z, v.w);
      *(uint2*)(&lpl[rl * WWn + c4 * 4]) = pk;
    }
  }

  // 49 weights -> SGPRs (uniform per block)
  float wk[49];
  const float* kc = hk + c * 49;
#pragma unroll
  for (int i = 0; i < 49; ++i)
    wk[i] = __uint_as_float(__builtin_amdgcn_readfirstlane(__float_as_uint(kc[i])));

  __syncthreads();
  if (tid >= 112) return;            // no barriers after this point

  int q = tid / 28;                  // 7-row chunk 0..3
  int s = tid % 28;                  // 4-col strip
  int cb = s * 4;                    // window cols cb-3..cb+6
  int qb = q * 7;                    // local output-row base
  bool aok0 = (s > 0);
  bool cok0 = (s < 27);
  int e0 = aok0 ? cb - 4 : 0;        // first b64 elem offset (clamped)
  int e2 = cok0 ? cb + 4 : cb;       // last  b64 elem offset (clamped)

  float acc[7][4];
#pragma unroll
  for (int i = 0; i < 7; ++i)
#pragma unroll
    for (int j = 0; j < 4; ++j) acc[i][j] = 0.f;

#pragma unroll
  for (int rr = 0; rr < 13; ++rr) {       // input rows (global) r0+qb+rr-3
    int g = r0 + qb + rr - 3;
    bool vok = ((unsigned)g < (unsigned)HHn);
    const unsigned short* rowp = &lpl[(qb + rr) * WWn];   // local row qb+rr
    uint2 U0 = *(const uint2*)(rowp + e0);   // cols cb-4..cb-1
    uint2 U1 = *(const uint2*)(rowp + cb);   // cols cb  ..cb+3
    uint2 U2 = *(const uint2*)(rowp + e2);   // cols cb+4..cb+7
    if (!(vok && aok0)) { U0.x = 0u; U0.y = 0u; }
    if (!vok)           { U1.x = 0u; U1.y = 0u; }
    if (!(vok && cok0)) { U2.x = 0u; U2.y = 0u; }

    float win[12];                    // win[w] = x col cb-4+w
    win[0]  = bflo(U0.x); win[1]  = bfhi(U0.x);
    win[2]  = bflo(U0.y); win[3]  = bfhi(U0.y);
    win[4]  = bflo(U1.x); win[5]  = bfhi(U1.x);
    win[6]  = bflo(U1.y); win[7]  = bfhi(U1.y);
    win[8]  = bflo(U2.x); win[9]  = bfhi(U2.x);
    win[10] = bflo(U2.y); win[11] = bfhi(U2.y);

    // input row rr feeds output slot = rr-kh (compile-time indices)
#pragma unroll
    for (int kh = 0; kh < 7; ++kh) {
      if (rr >= kh && rr - kh <= 6) {
        const int slot = rr - kh;
#pragma unroll
        for (int kw = 0; kw < 7; ++kw) {
          float wv = wk[kh * 7 + kw];
#pragma unroll
          for (int j = 0; j < 4; ++j)
            acc[slot][j] = fmaf(win[1 + kw + j], wv, acc[slot][j]);
        }
      }
    }

    if (rr >= 6) {                        // output row r0+qb+rr-6 complete
      const int slot = rr - 6;
      unsigned short* orow = fp + (r0 + qb + slot) * WWn + cb;
      uint2 pk;
      pk.x = pkbf(acc[slot][0], acc[slot][1]);
      pk.y = pkbf(acc[slot][2], acc[slot][3]);
      *(uint2*)orow = pk;
    }
  }
}

// ------- MFMA 1x1 mix (bf16) + fused BN stats, 256 px/block -------
__global__ __launch_bounds__(256, 2) void k_mix(const unsigned short* __restrict__ feat,
                                                const unsigned short* __restrict__ wbf,
                                                unsigned short* __restrict__ mixed,
                                                float* __restrict__ ssum,
                                                float* __restrict__ ssq) {
  __shared__ unsigned short flds[256 * 128];   // 64 KB; reused for out-transpose
  __shared__ float lsum[CC], lsq[CC];

  int tid = threadIdx.x;
  int bid = blockIdx.x;
  int b = bid / 49, tile = bid % 49;
  int p0 = tile * 256;

  if (tid < CC) { lsum[tid] = 0.f; lsq[tid] = 0.f; }

  const unsigned short* fb = feat + (long)b * CC * HWn + p0;
  int u   = (tid >> 3) & 7;        // c within group of 8
  int v   = tid & 7;               // pixel-group low
  int wv  = tid >> 6;              // wave 0..3
  int pgl = wv * 8 + v;            // pixel-group 0..31 (8 px each)

  bf16x8 vals[12];
#pragma unroll
  for (int s = 0; s < 12; ++s) {
    int c = s * 8 + u;
    vals[s] = *(const bf16x8*)(fb + (long)c * HWn + pgl * 8);
  }
#pragma unroll
  for (int s = 0; s < 12; ++s) {
#pragma unroll
    for (int e = 0; e < 8; ++e) {
      int pl = pgl * 8 + e;
      int kp = (pl ^ (pl >> 3)) & 7;
      flds[pl * 128 + ((s ^ kp) << 3) + u] = (unsigned short)vals[s][e];
    }
  }

  int l = tid & 63;
  int lm = l & 15, lg = l >> 4;
  bf16x8 a[6][3];
#pragma unroll
  for (int mt = 0; mt < 6; ++mt)
#pragma unroll
    for (int kk = 0; kk < 3; ++kk)
      a[mt][kk] = *(const bf16x8*)(wbf + (mt * 16 + lm) * CC + kk * 32 + lg * 8);

  __syncthreads();

  f32x4 acc[6][4];
#pragma unroll
  for (int mt = 0; mt < 6; ++mt)
#pragma unroll
    for (int j = 0; j < 4; ++j) acc[mt][j] = (f32x4){0.f, 0.f, 0.f, 0.f};

#pragma unroll
  for (int j = 0; j < 4; ++j) {
    int pl = (wv * 4 + j) * 16 + lm;
    int kp = (pl ^ (pl >> 3)) & 7;
#pragma unroll
    for (int kk = 0; kk < 3; ++kk) {
      bf16x8 bfrag = *(const bf16x8*)(&flds[pl * 128 + (((kk * 4 + lg) ^ kp) << 3)]);
#pragma unroll
      for (int mt = 0; mt < 6; ++mt)
        acc[mt][j] = __builtin_amdgcn_mfma_f32_16x16x32_bf16(a[mt][kk], bfrag, acc[mt][j], 0, 0, 0);
    }
  }

  __syncthreads();   // staging reads complete; reuse flds as [o][px'] u16

#pragma unroll
  for (int mt = 0; mt < 6; ++mt) {
#pragma unroll
    for (int r = 0; r < 4; ++r) {
      int o = mt * 16 + lg * 4 + r;          // (o>>2)&3 == lg
      float s = 0.f, q = 0.f;
#pragma unroll
      for (int j = 0; j < 4; ++j) {
        unsigned short h = f2bf(acc[mt][j][r]);
        float vv = bf2f(h);
        int px = (wv * 4 + j) * 16 + lm;
        flds[o * 256 + (px ^ (lg << 4))] = h;
        s += vv; q += vv * vv;
      }
      s += __shfl_xor(s, 1); q += __shfl_xor(q, 1);
      s += __shfl_xor(s, 2); q += __shfl_xor(q, 2);
      s += __shfl_xor(s, 4); q += __shfl_xor(q, 4);
      s += __shfl_xor(s, 8); q += __shfl_xor(q, 8);
      if (lm == 0) { atomicAdd(&lsum[o], s); atomicAdd(&lsq[o], q); }
    }
  }
  __syncthreads();

  unsigned short* mbase = mixed + (long)b * CC * HWn + p0;
  int o2 = tid >> 5;          // 0..7
  int pxg = tid & 31;         // 8-px group
#pragma unroll
  for (int i = 0; i < 12; ++i) {
    int o = i * 8 + o2;
    int key = (o >> 2) & 3;
    uint4 vv = *(const uint4*)(&flds[o * 256 + ((pxg * 8) ^ (key << 4))]);
    *(uint4*)(mbase + (long)o * HWn + pxg * 8) = vv;
  }

  if (tid < CC) atomicAdd(&ssum[tid], lsum[tid]);
  else if (tid < 2 * CC) atomicAdd(&ssq[tid - CC], lsq[tid - CC]);
}

__global__ void k_finalize(const float* __restrict__ ssum,
                           const float* __restrict__ ssq,
                           float* __restrict__ meanv,
                           float* __restrict__ rstdv) {
  int o = threadIdx.x;
  if (o < CC) {
    float m = ssum[o] * (1.0f / NPIX);
    float v = ssq[o] * (1.0f / NPIX) - m * m;
    meanv[o] = m;
    rstdv[o] = 1.0f / sqrtf(v + EPSf);
  }
}

// ---------------- BN (affine=False) + exact GELU, bf16 in / f32 out --------
__global__ __launch_bounds__(256) void k_bngelu(const unsigned short* __restrict__ mixed,
                                                const float* __restrict__ meanv,
                                                const float* __restrict__ rstdv,
                                                float* __restrict__ out) {
  long e = ((long)blockIdx.x * 256 + threadIdx.x) * 8;
  int o = (int)((e / HWn) % CC);       // 12544 % 8 == 0 -> same plane
  float m = meanv[o], r = rstdv[o];
  bf16x8 v = *(const bf16x8*)(mixed + e);
  float4 g0, g1;
  float z;
  z = (bf2f((unsigned short)v[0]) - m) * r; g0.x = 0.5f * z * (1.0f + erff(z * 0.70710678f));
  z = (bf2f((unsigned short)v[1]) - m) * r; g0.y = 0.5f * z * (1.0f + erff(z * 0.70710678f));
  z = (bf2f((unsigned short)v[2]) - m) * r; g0.z = 0.5f * z * (1.0f + erff(z * 0.70710678f));
  z = (bf2f((unsigned short)v[3]) - m) * r; g0.w = 0.5f * z * (1.0f + erff(z * 0.70710678f));
  z = (bf2f((unsigned short)v[4]) - m) * r; g1.x = 0.5f * z * (1.0f + erff(z * 0.70710678f));
  z = (bf2f((unsigned short)v[5]) - m) * r; g1.y = 0.5f * z * (1.0f + erff(z * 0.70710678f));
  z = (bf2f((unsigned short)v[6]) - m) * r; g1.z = 0.5f * z * (1.0f + erff(z * 0.70710678f));
  z = (bf2f((unsigned short)v[7]) - m) * r; g1.w = 0.5f * z * (1.0f + erff(z * 0.70710678f));
  *(float4*)(out + e)     = g0;
  *(float4*)(out + e + 4) = g1;
}

extern "C" void kernel_launch(void* const* d_in, const int* in_sizes, int n_in,
                              void* d_out, int out_size, void* d_ws, size_t ws_size,
                              hipStream_t stream) {
  const float* hk   = (const float*)d_in[0];   // local_hk [96,1,7,7]
  const float* x    = (const float*)d_in[1];   // x [32,96,112,112]
  const float* wmix = (const float*)d_in[2];   // w_mix [96,96]
  const float* bmix = (const float*)d_in[3];   // b_mix [96] (cancels in BN)
  (void)bmix;
  float* out = (float*)d_out;

  char* ws = (char*)d_ws;
  float* stats = (float*)ws;                           // sum,ssq,mean,rstd [96] each
  unsigned short* wbf     = (unsigned short*)(ws + 2048);            // 18432 B
  unsigned short* featbf  = (unsigned short*)(ws + 32768);           // 77,070,336 B
  unsigned short* mixedbf = (unsigned short*)(ws + 32768 + 77070336);

  hipMemsetAsync(stats, 0, 768, stream);       // zero sum+ssq each call

  k_prep<<<36, 256, 0, stream>>>(wmix, wbf);
  k_conv<<<12288, 128, 0, stream>>>(x, hk, featbf);
  k_mix<<<1568, 256, 0, stream>>>(featbf, wbf, mixedbf, stats, stats + 96);
  k_finalize<<<1, 128, 0, stream>>>(stats, stats + 96, stats + 192, stats + 288);
  k_bngelu<<<18816, 256, 0, stream>>>(mixedbf, stats + 192, stats + 288, out);
}

// Round 17
// 190.709 us; speedup vs baseline: 1.0998x; 1.0998x over previous
//
#include <hip/hip_runtime.h>
#include <hip/hip_bf16.h>
#include <cstdint>
#include <cstddef>

#define CC   96
#define BB   32
#define HHn  112
#define WWn  112
#define HWn  (HHn*WWn)        // 12544
#define NPIX (BB*HWn)         // 401408
#define EPSf 1e-5f

typedef __attribute__((ext_vector_type(8))) short bf16x8;
typedef __attribute__((ext_vector_type(4))) float f32x4;
typedef __attribute__((ext_vector_type(2))) float f32x2;

__device__ inline unsigned short f2bf(float f) {      // RNE f32 -> bf16 (bit math)
  unsigned u = __float_as_uint(f);
  return (unsigned short)((u + 0x7FFFu + ((u >> 16) & 1u)) >> 16);
}
__device__ inline float bf2f(unsigned short h) {
  return __uint_as_float(((unsigned)h) << 16);
}
__device__ inline float bflo(unsigned u) { return __uint_as_float(u << 16); }
__device__ inline float bfhi(unsigned u) { return __uint_as_float(u & 0xffff0000u); }
__device__ inline unsigned pkbf(float a, float b) {   // v_cvt_pk_bf16_f32 (RNE)
  __hip_bfloat162 h = __float22bfloat162_rn(float2{a, b});
  return *reinterpret_cast<unsigned*>(&h);
}

// ---------------- w_mix f32[o][c] -> bf16[o][c] ----------------
__global__ __launch_bounds__(256) void k_prep(const float* __restrict__ w,
                                              unsigned short* __restrict__ wbf) {
  int i = blockIdx.x * 256 + threadIdx.x;
  if (i < CC * CC) wbf[i] = f2bf(w[i]);
}

// ---------------- depthwise 7x7 conv: bf16 LDS plane + packed f32 FMA -------
// Block = one (b,c) plane, 512 threads; plane staged as bf16 (25 KB LDS).
// 448 active items: q=tid/28 (7-row chunk), s=tid%28 (4-col strip).
// Per input row: 3x ds_read_b64 -> 6 packed words W0..W5; 5 shifts build
// odd-aligned S0..S4; unpack to 11 float2 pairs (pe/po); per (kh,kw):
// 2 packed f32 FMAs (f32x2 + __builtin_elementwise_fma -> v_pk_fma_f32),
// halving FMA instruction count vs r14. Bit-identical f32 math to r14.
__global__ __launch_bounds__(512, 4) void k_conv(const float* __restrict__ x,
                                                 const float* __restrict__ hk,
                                                 unsigned short* __restrict__ feat) {
  __shared__ unsigned short lpl[HWn];   // 25,088 B

  int tid = threadIdx.x;
  int plane = __builtin_amdgcn_readfirstlane(blockIdx.x);   // (b*C+c)
  int c = plane % CC;
  const float* xp = x + (long)plane * HWn;
  unsigned short* fp = feat + (long)plane * HWn;

  // ---- stage full plane f32 -> bf16: 3136 float4 = 6*512 + 64 ----
#pragma unroll
  for (int it = 0; it < 6; ++it) {
    int idx = it * 512 + tid;
    float4 v = *(const float4*)(xp + idx * 4);
    uint2 pk;
    pk.x = pkbf(v.x, v.y);
    pk.y = pkbf(v.z, v.w);
    *(uint2*)(&lpl[idx * 4]) = pk;
  }
  if (tid < 64) {
    int idx = 3072 + tid;
    float4 v = *(const float4*)(xp + idx * 4);
    uint2 pk;
    pk.x = pkbf(v.x, v.y);
    pk.y = pkbf(v.z, v.w);
    *(uint2*)(&lpl[idx * 4]) = pk;
  }

  // 49 weights -> SGPRs (uniform per block)
  float wk[49];
  const float* kc = hk + c * 49;
#pragma unroll
  for (int i = 0; i < 49; ++i)
    wk[i] = __uint_as_float(__builtin_amdgcn_readfirstlane(__float_as_uint(kc[i])));

  __syncthreads();
  if (tid >= 448) return;            // no barriers after this point

  int q = tid / 28;                  // 7-row chunk 0..15
  int s = tid % 28;                  // 4-col strip
  int cb = s * 4;                    // window cols cb-3..cb+6
  int qb = q * 7;                    // first output row of this item
  bool aok0 = (s > 0);
  bool cok0 = (s < 27);
  int e0 = aok0 ? cb - 4 : 0;        // first b64 elem offset (clamped)
  int e2 = cok0 ? cb + 4 : cb;       // last  b64 elem offset (clamped)

  f32x2 acc2[7][2];                  // [slot][pair]: pair0=(px0,px1) pair1=(px2,px3)
#pragma unroll
  for (int i = 0; i < 7; ++i) {
    acc2[i][0] = (f32x2){0.f, 0.f};
    acc2[i][1] = (f32x2){0.f, 0.f};
  }

#pragma unroll
  for (int rr = 0; rr < 13; ++rr) {       // input rows qb+rr-3
    int g = qb + rr - 3;
    bool vok = ((unsigned)g < (unsigned)HHn);
    int gc = g < 0 ? 0 : (g > HHn - 1 ? HHn - 1 : g);
    const unsigned short* rowp = &lpl[gc * WWn];
    uint2 U0 = *(const uint2*)(rowp + e0);   // cols cb-4..cb-1
    uint2 U1 = *(const uint2*)(rowp + cb);   // cols cb  ..cb+3
    uint2 U2 = *(const uint2*)(rowp + e2);   // cols cb+4..cb+7
    if (!(vok && aok0)) { U0.x = 0u; U0.y = 0u; }
    if (!vok)           { U1.x = 0u; U1.y = 0u; }
    if (!(vok && cok0)) { U2.x = 0u; U2.y = 0u; }

    // packed window: W[i] = (rel[2i] lo, rel[2i+1] hi), rel[w] = col cb-4+w
    unsigned W0 = U0.x, W1 = U0.y, W2 = U1.x, W3 = U1.y, W4 = U2.x, W5 = U2.y;
    // odd-aligned: S[i] = (rel[2i+1], rel[2i+2])
    unsigned S0 = (W0 >> 16) | (W1 << 16);
    unsigned S1 = (W1 >> 16) | (W2 << 16);
    unsigned S2 = (W2 >> 16) | (W3 << 16);
    unsigned S3 = (W3 >> 16) | (W4 << 16);
    unsigned S4 = (W4 >> 16) | (W5 << 16);

    f32x2 pe[6], po[5];               // pe[i]=(rel2i,rel2i+1)  po[i]=(rel2i+1,rel2i+2)
    pe[0] = (f32x2){bflo(W0), bfhi(W0)};
    pe[1] = (f32x2){bflo(W1), bfhi(W1)};
    pe[2] = (f32x2){bflo(W2), bfhi(W2)};
    pe[3] = (f32x2){bflo(W3), bfhi(W3)};
    pe[4] = (f32x2){bflo(W4), bfhi(W4)};
    pe[5] = (f32x2){bflo(W5), bfhi(W5)};
    po[0] = (f32x2){bflo(S0), bfhi(S0)};
    po[1] = (f32x2){bflo(S1), bfhi(S1)};
    po[2] = (f32x2){bflo(S2), bfhi(S2)};
    po[3] = (f32x2){bflo(S3), bfhi(S3)};
    po[4] = (f32x2){bflo(S4), bfhi(S4)};

    // out px j needs rel[1+kw+j]; pairs (px0,px1) and (px2,px3):
    //   (rel[1+kw],rel[2+kw]) = kw odd ? pe[(kw+1)/2] : po[kw/2]
    //   (rel[3+kw],rel[4+kw]) = kw odd ? pe[(kw+3)/2] : po[kw/2+1]
#pragma unroll
    for (int kh = 0; kh < 7; ++kh) {
      if (rr >= kh && rr - kh <= 6) {
        const int slot = rr - kh;
#pragma unroll
        for (int kw = 0; kw < 7; ++kw) {
          float wv = wk[kh * 7 + kw];
          f32x2 w2 = (f32x2){wv, wv};
          f32x2 p01 = (kw & 1) ? pe[(kw + 1) >> 1] : po[kw >> 1];
          f32x2 p23 = (kw & 1) ? pe[(kw + 3) >> 1] : po[(kw >> 1) + 1];
          acc2[slot][0] = __builtin_elementwise_fma(p01, w2, acc2[slot][0]);
          acc2[slot][1] = __builtin_elementwise_fma(p23, w2, acc2[slot][1]);
        }
      }
    }

    if (rr >= 6) {                        // output row qb+rr-6 complete
      const int slot = rr - 6;
      unsigned short* orow = fp + (qb + slot) * WWn + cb;
      uint2 pk;
      pk.x = pkbf(acc2[slot][0][0], acc2[slot][0][1]);
      pk.y = pkbf(acc2[slot][1][0], acc2[slot][1][1]);
      *(uint2*)orow = pk;
    }
  }
}

// ------- MFMA 1x1 mix (bf16) + fused BN stats, 256 px/block -------
__global__ __launch_bounds__(256, 2) void k_mix(const unsigned short* __restrict__ feat,
                                                const unsigned short* __restrict__ wbf,
                                                unsigned short* __restrict__ mixed,
                                                float* __restrict__ ssum,
                                                float* __restrict__ ssq) {
  __shared__ unsigned short flds[256 * 128];   // 64 KB; reused for out-transpose
  __shared__ float lsum[CC], lsq[CC];

  int tid = threadIdx.x;
  int bid = blockIdx.x;
  int b = bid / 49, tile = bid % 49;
  int p0 = tile * 256;

  if (tid < CC) { lsum[tid] = 0.f; lsq[tid] = 0.f; }

  const unsigned short* fb = feat + (long)b * CC * HWn + p0;
  int u   = (tid >> 3) & 7;        // c within group of 8
  int v   = tid & 7;               // pixel-group low
  int wv  = tid >> 6;              // wave 0..3
  int pgl = wv * 8 + v;            // pixel-group 0..31 (8 px each)

  bf16x8 vals[12];
#pragma unroll
  for (int s = 0; s < 12; ++s) {
    int c = s * 8 + u;
    vals[s] = *(const bf16x8*)(fb + (long)c * HWn + pgl * 8);
  }
#pragma unroll
  for (int s = 0; s < 12; ++s) {
#pragma unroll
    for (int e = 0; e < 8; ++e) {
      int pl = pgl * 8 + e;
      int kp = (pl ^ (pl >> 3)) & 7;
      flds[pl * 128 + ((s ^ kp) << 3) + u] = (unsigned short)vals[s][e];
    }
  }

  int l = tid & 63;
  int lm = l & 15, lg = l >> 4;
  bf16x8 a[6][3];
#pragma unroll
  for (int mt = 0; mt < 6; ++mt)
#pragma unroll
    for (int kk = 0; kk < 3; ++kk)
      a[mt][kk] = *(const bf16x8*)(wbf + (mt * 16 + lm) * CC + kk * 32 + lg * 8);

  __syncthreads();

  f32x4 acc[6][4];
#pragma unroll
  for (int mt = 0; mt < 6; ++mt)
#pragma unroll
    for (int j = 0; j < 4; ++j) acc[mt][j] = (f32x4){0.f, 0.f, 0.f, 0.f};

#pragma unroll
  for (int j = 0; j < 4; ++j) {
    int pl = (wv * 4 + j) * 16 + lm;
    int kp = (pl ^ (pl >> 3)) & 7;
#pragma unroll
    for (int kk = 0; kk < 3; ++kk) {
      bf16x8 bfrag = *(const bf16x8*)(&flds[pl * 128 + (((kk * 4 + lg) ^ kp) << 3)]);
#pragma unroll
      for (int mt = 0; mt < 6; ++mt)
        acc[mt][j] = __builtin_amdgcn_mfma_f32_16x16x32_bf16(a[mt][kk], bfrag, acc[mt][j], 0, 0, 0);
    }
  }

  __syncthreads();   // staging reads complete; reuse flds as [o][px'] u16

#pragma unroll
  for (int mt = 0; mt < 6; ++mt) {
#pragma unroll
    for (int r = 0; r < 4; ++r) {
      int o = mt * 16 + lg * 4 + r;          // (o>>2)&3 == lg
      float s = 0.f, q = 0.f;
#pragma unroll
      for (int j = 0; j < 4; ++j) {
        unsigned short h = f2bf(acc[mt][j][r]);
        float vv = bf2f(h);
        int px = (wv * 4 + j) * 16 + lm;
        flds[o * 256 + (px ^ (lg << 4))] = h;
        s += vv; q += vv * vv;
      }
      s += __shfl_xor(s, 1); q += __shfl_xor(q, 1);
      s += __shfl_xor(s, 2); q += __shfl_xor(q, 2);
      s += __shfl_xor(s, 4); q += __shfl_xor(q, 4);
      s += __shfl_xor(s, 8); q += __shfl_xor(q, 8);
      if (lm == 0) { atomicAdd(&lsum[o], s); atomicAdd(&lsq[o], q); }
    }
  }
  __syncthreads();

  unsigned short* mbase = mixed + (long)b * CC * HWn + p0;
  int o2 = tid >> 5;          // 0..7
  int pxg = tid & 31;         // 8-px group
#pragma unroll
  for (int i = 0; i < 12; ++i) {
    int o = i * 8 + o2;
    int key = (o >> 2) & 3;
    uint4 vv = *(const uint4*)(&flds[o * 256 + ((pxg * 8) ^ (key << 4))]);
    *(uint4*)(mbase + (long)o * HWn + pxg * 8) = vv;
  }

  if (tid < CC) atomicAdd(&ssum[tid], lsum[tid]);
  else if (tid < 2 * CC) atomicAdd(&ssq[tid - CC], lsq[tid - CC]);
}

__global__ void k_finalize(const float* __restrict__ ssum,
                           const float* __restrict__ ssq,
                           float* __restrict__ meanv,
                           float* __restrict__ rstdv) {
  int o = threadIdx.x;
  if (o < CC) {
    float m = ssum[o] * (1.0f / NPIX);
    float v = ssq[o] * (1.0f / NPIX) - m * m;
    meanv[o] = m;
    rstdv[o] = 1.0f / sqrtf(v + EPSf);
  }
}

// ---------------- BN (affine=False) + exact GELU, bf16 in / f32 out --------
__global__ __launch_bounds__(256) void k_bngelu(const unsigned short* __restrict__ mixed,
                                                const float* __restrict__ meanv,
                                                const float* __restrict__ rstdv,
                                                float* __restrict__ out) {
  long e = ((long)blockIdx.x * 256 + threadIdx.x) * 8;
  int o = (int)((e / HWn) % CC);       // 12544 % 8 == 0 -> same plane
  float m = meanv[o], r = rstdv[o];
  bf16x8 v = *(const bf16x8*)(mixed + e);
  float4 g0, g1;
  float z;
  z = (bf2f((unsigned short)v[0]) - m) * r; g0.x = 0.5f * z * (1.0f + erff(z * 0.70710678f));
  z = (bf2f((unsigned short)v[1]) - m) * r; g0.y = 0.5f * z * (1.0f + erff(z * 0.70710678f));
  z = (bf2f((unsigned short)v[2]) - m) * r; g0.z = 0.5f * z * (1.0f + erff(z * 0.70710678f));
  z = (bf2f((unsigned short)v[3]) - m) * r; g0.w = 0.5f * z * (1.0f + erff(z * 0.70710678f));
  z = (bf2f((unsigned short)v[4]) - m) * r; g1.x = 0.5f * z * (1.0f + erff(z * 0.70710678f));
  z = (bf2f((unsigned short)v[5]) - m) * r; g1.y = 0.5f * z * (1.0f + erff(z * 0.70710678f));
  z = (bf2f((unsigned short)v[6]) - m) * r; g1.z = 0.5f * z * (1.0f + erff(z * 0.70710678f));
  z = (bf2f((unsigned short)v[7]) - m) * r; g1.w = 0.5f * z * (1.0f + erff(z * 0.70710678f));
  *(float4*)(out + e)     = g0;
  *(float4*)(out + e + 4) = g1;
}

extern "C" void kernel_launch(void* const* d_in, const int* in_sizes, int n_in,
                              void* d_out, int out_size, void* d_ws, size_t ws_size,
                              hipStream_t stream) {
  const float* hk   = (const float*)d_in[0];   // local_hk [96,1,7,7]
  const float* x    = (const float*)d_in[1];   // x [32,96,112,112]
  const float* wmix = (const float*)d_in[2];   // w_mix [96,96]
  const float* bmix = (const float*)d_in[3];   // b_mix [96] (cancels in BN)
  (void)bmix;
  float* out = (float*)d_out;

  char* ws = (char*)d_ws;
  float* stats = (float*)ws;                           // sum,ssq,mean,rstd [96] each
  unsigned short* wbf     = (unsigned short*)(ws + 2048);            // 18432 B
  unsigned short* featbf  = (unsigned short*)(ws + 32768);           // 77,070,336 B
  unsigned short* mixedbf = (unsigned short*)(ws + 32768 + 77070336);

  hipMemsetAsync(stats, 0, 768, stream);       // zero sum+ssq each call

  k_prep<<<36, 256, 0, stream>>>(wmix, wbf);
  k_conv<<<3072, 512, 0, stream>>>(x, hk, featbf);
  k_mix<<<1568, 256, 0, stream>>>(featbf, wbf, mixedbf, stats, stats + 96);
  k_finalize<<<1, 128, 0, stream>>>(stats, stats + 96, stats + 192, stats + 288);
  k_bngelu<<<18816, 256, 0, stream>>>(mixedbf, stats + 192, stats + 288, out);
}

// Round 18
// 181.045 us; speedup vs baseline: 1.1585x; 1.0534x over previous
//
#include <hip/hip_runtime.h>
#include <hip/hip_bf16.h>
#include <cstdint>
#include <cstddef>

#define CC   96
#define BB   32
#define HHn  112
#define WWn  112
#define HWn  (HHn*WWn)        // 12544
#define NPIX (BB*HWn)         // 401408
#define EPSf 1e-5f

typedef __attribute__((ext_vector_type(8))) short bf16x8;
typedef __attribute__((ext_vector_type(4))) float f32x4;
typedef __attribute__((ext_vector_type(2))) float f32x2;

__device__ inline unsigned short f2bf(float f) {      // RNE f32 -> bf16 (bit math)
  unsigned u = __float_as_uint(f);
  return (unsigned short)((u + 0x7FFFu + ((u >> 16) & 1u)) >> 16);
}
__device__ inline float bf2f(unsigned short h) {
  return __uint_as_float(((unsigned)h) << 16);
}
__device__ inline float bflo(unsigned u) { return __uint_as_float(u << 16); }
__device__ inline float bfhi(unsigned u) { return __uint_as_float(u & 0xffff0000u); }
__device__ inline unsigned pkbf(float a, float b) {   // v_cvt_pk_bf16_f32 (RNE)
  __hip_bfloat162 h = __float22bfloat162_rn(float2{a, b});
  return *reinterpret_cast<unsigned*>(&h);
}

// ---------------- w_mix f32[o][c] -> bf16[o][c] ----------------
__global__ __launch_bounds__(256) void k_prep(const float* __restrict__ w,
                                              unsigned short* __restrict__ wbf) {
  int i = blockIdx.x * 256 + threadIdx.x;
  if (i < CC * CC) wbf[i] = f2bf(w[i]);
}

// ---------------- depthwise 7x7 conv: bf16 LDS plane, 3-deep LDS prefetch ----
// Block = one (b,c) plane, 512 threads; plane staged as bf16 (25 KB LDS).
// 448 active items: q=tid/28 (7-row chunk), s=tid%28 (4-col strip).
// Rotating U[3][3] register pipeline: row rr's 3x ds_read_b64 are issued 3
// steps ahead of consumption (9 reads in flight), hiding ~120cyc LDS latency
// under the per-row FMA work (the r9-r17 plateau's per-row-step
// ds_read->lgkmcnt(0)->consume chains were the hypothesized stall).
// Packed f32x2 FMA (bit-identical to scalar f32).
__global__ __launch_bounds__(512, 4) void k_conv(const float* __restrict__ x,
                                                 const float* __restrict__ hk,
                                                 unsigned short* __restrict__ feat) {
  __shared__ unsigned short lpl[HWn];   // 25,088 B

  int tid = threadIdx.x;
  int plane = __builtin_amdgcn_readfirstlane(blockIdx.x);   // (b*C+c)
  int c = plane % CC;
  const float* xp = x + (long)plane * HWn;
  unsigned short* fp = feat + (long)plane * HWn;

  // ---- stage full plane f32 -> bf16: 3136 float4 = 6*512 + 64 ----
#pragma unroll
  for (int it = 0; it < 6; ++it) {
    int idx = it * 512 + tid;
    float4 v = *(const float4*)(xp + idx * 4);
    uint2 pk;
    pk.x = pkbf(v.x, v.y);
    pk.y = pkbf(v.z, v.w);
    *(uint2*)(&lpl[idx * 4]) = pk;
  }
  if (tid < 64) {
    int idx = 3072 + tid;
    float4 v = *(const float4*)(xp + idx * 4);
    uint2 pk;
    pk.x = pkbf(v.x, v.y);
    pk.y = pkbf(v.z, v.w);
    *(uint2*)(&lpl[idx * 4]) = pk;
  }

  // 49 weights -> SGPRs (uniform per block)
  float wk[49];
  const float* kc = hk + c * 49;
#pragma unroll
  for (int i = 0; i < 49; ++i)
    wk[i] = __uint_as_float(__builtin_amdgcn_readfirstlane(__float_as_uint(kc[i])));

  __syncthreads();
  if (tid >= 448) return;            // no barriers after this point

  int q = tid / 28;                  // 7-row chunk 0..15
  int s = tid % 28;                  // 4-col strip
  int cb = s * 4;                    // window cols cb-3..cb+6
  int qb = q * 7;                    // first output row of this item
  bool aok0 = (s > 0);
  bool cok0 = (s < 27);
  int e0 = aok0 ? cb - 4 : 0;        // first b64 elem offset (clamped)
  int e2 = cok0 ? cb + 4 : cb;       // last  b64 elem offset (clamped)

  f32x2 acc2[7][2];                  // [slot][pair]: pair0=(px0,px1) pair1=(px2,px3)
#pragma unroll
  for (int i = 0; i < 7; ++i) {
    acc2[i][0] = (f32x2){0.f, 0.f};
    acc2[i][1] = (f32x2){0.f, 0.f};
  }

  // ---- rotating 3-deep LDS row prefetch: row r lives in slot r%3 ----
  uint2 U[3][3];
#define ISSUE_ROW(slot, row)                                             \
  {                                                                      \
    int g_ = qb + (row)-3;                                               \
    int gc_ = g_ < 0 ? 0 : (g_ > HHn - 1 ? HHn - 1 : g_);                \
    const unsigned short* rp_ = &lpl[gc_ * WWn];                         \
    U[slot][0] = *(const uint2*)(rp_ + e0);                              \
    U[slot][1] = *(const uint2*)(rp_ + cb);                              \
    U[slot][2] = *(const uint2*)(rp_ + e2);                              \
  }

  ISSUE_ROW(0, 0)
  ISSUE_ROW(1, 1)
  ISSUE_ROW(2, 2)

#pragma unroll
  for (int rr = 0; rr < 13; ++rr) {       // input rows qb+rr-3
    int g = qb + rr - 3;
    bool vok = ((unsigned)g < (unsigned)HHn);
    uint2 U0 = U[rr % 3][0];   // cols cb-4..cb-1
    uint2 U1 = U[rr % 3][1];   // cols cb  ..cb+3
    uint2 U2 = U[rr % 3][2];   // cols cb+4..cb+7
    if (!(vok && aok0)) { U0.x = 0u; U0.y = 0u; }
    if (!vok)           { U1.x = 0u; U1.y = 0u; }
    if (!(vok && cok0)) { U2.x = 0u; U2.y = 0u; }

    // issue row rr+3 into the slot just freed
    if (rr + 3 < 13) ISSUE_ROW(rr % 3, rr + 3)

    // packed window: W[i] = (rel[2i] lo, rel[2i+1] hi), rel[w] = col cb-4+w
    unsigned W0 = U0.x, W1 = U0.y, W2 = U1.x, W3 = U1.y, W4 = U2.x, W5 = U2.y;
    // odd-aligned: S[i] = (rel[2i+1], rel[2i+2])
    unsigned S0 = (W0 >> 16) | (W1 << 16);
    unsigned S1 = (W1 >> 16) | (W2 << 16);
    unsigned S2 = (W2 >> 16) | (W3 << 16);
    unsigned S3 = (W3 >> 16) | (W4 << 16);
    unsigned S4 = (W4 >> 16) | (W5 << 16);

    f32x2 pe[6], po[5];               // pe[i]=(rel2i,rel2i+1)  po[i]=(rel2i+1,rel2i+2)
    pe[0] = (f32x2){bflo(W0), bfhi(W0)};
    pe[1] = (f32x2){bflo(W1), bfhi(W1)};
    pe[2] = (f32x2){bflo(W2), bfhi(W2)};
    pe[3] = (f32x2){bflo(W3), bfhi(W3)};
    pe[4] = (f32x2){bflo(W4), bfhi(W4)};
    pe[5] = (f32x2){bflo(W5), bfhi(W5)};
    po[0] = (f32x2){bflo(S0), bfhi(S0)};
    po[1] = (f32x2){bflo(S1), bfhi(S1)};
    po[2] = (f32x2){bflo(S2), bfhi(S2)};
    po[3] = (f32x2){bflo(S3), bfhi(S3)};
    po[4] = (f32x2){bflo(S4), bfhi(S4)};

    // out px j needs rel[1+kw+j]; pairs (px0,px1) and (px2,px3)
#pragma unroll
    for (int kh = 0; kh < 7; ++kh) {
      if (rr >= kh && rr - kh <= 6) {
        const int slot = rr - kh;
#pragma unroll
        for (int kw = 0; kw < 7; ++kw) {
          float wv = wk[kh * 7 + kw];
          f32x2 w2 = (f32x2){wv, wv};
          f32x2 p01 = (kw & 1) ? pe[(kw + 1) >> 1] : po[kw >> 1];
          f32x2 p23 = (kw & 1) ? pe[(kw + 3) >> 1] : po[(kw >> 1) + 1];
          acc2[slot][0] = __builtin_elementwise_fma(p01, w2, acc2[slot][0]);
          acc2[slot][1] = __builtin_elementwise_fma(p23, w2, acc2[slot][1]);
        }
      }
    }

    if (rr >= 6) {                        // output row qb+rr-6 complete
      const int slot = rr - 6;
      unsigned short* orow = fp + (qb + slot) * WWn + cb;
      uint2 pk;
      pk.x = pkbf(acc2[slot][0][0], acc2[slot][0][1]);
      pk.y = pkbf(acc2[slot][1][0], acc2[slot][1][1]);
      *(uint2*)orow = pk;
    }
  }
#undef ISSUE_ROW
}

// ------- MFMA 1x1 mix (bf16) + fused BN stats, 256 px/block -------
__global__ __launch_bounds__(256, 2) void k_mix(const unsigned short* __restrict__ feat,
                                                const unsigned short* __restrict__ wbf,
                                                unsigned short* __restrict__ mixed,
                                                float* __restrict__ ssum,
                                                float* __restrict__ ssq) {
  __shared__ unsigned short flds[256 * 128];   // 64 KB; reused for out-transpose
  __shared__ float lsum[CC], lsq[CC];

  int tid = threadIdx.x;
  int bid = blockIdx.x;
  int b = bid / 49, tile = bid % 49;
  int p0 = tile * 256;

  if (tid < CC) { lsum[tid] = 0.f; lsq[tid] = 0.f; }

  const unsigned short* fb = feat + (long)b * CC * HWn + p0;
  int u   = (tid >> 3) & 7;        // c within group of 8
  int v   = tid & 7;               // pixel-group low
  int wv  = tid >> 6;              // wave 0..3
  int pgl = wv * 8 + v;            // pixel-group 0..31 (8 px each)

  bf16x8 vals[12];
#pragma unroll
  for (int s = 0; s < 12; ++s) {
    int c = s * 8 + u;
    vals[s] = *(const bf16x8*)(fb + (long)c * HWn + pgl * 8);
  }
#pragma unroll
  for (int s = 0; s < 12; ++s) {
#pragma unroll
    for (int e = 0; e < 8; ++e) {
      int pl = pgl * 8 + e;
      int kp = (pl ^ (pl >> 3)) & 7;
      flds[pl * 128 + ((s ^ kp) << 3) + u] = (unsigned short)vals[s][e];
    }
  }

  int l = tid & 63;
  int lm = l & 15, lg = l >> 4;
  bf16x8 a[6][3];
#pragma unroll
  for (int mt = 0; mt < 6; ++mt)
#pragma unroll
    for (int kk = 0; kk < 3; ++kk)
      a[mt][kk] = *(const bf16x8*)(wbf + (mt * 16 + lm) * CC + kk * 32 + lg * 8);

  __syncthreads();

  f32x4 acc[6][4];
#pragma unroll
  for (int mt = 0; mt < 6; ++mt)
#pragma unroll
    for (int j = 0; j < 4; ++j) acc[mt][j] = (f32x4){0.f, 0.f, 0.f, 0.f};

#pragma unroll
  for (int j = 0; j < 4; ++j) {
    int pl = (wv * 4 + j) * 16 + lm;
    int kp = (pl ^ (pl >> 3)) & 7;
#pragma unroll
    for (int kk = 0; kk < 3; ++kk) {
      bf16x8 bfrag = *(const bf16x8*)(&flds[pl * 128 + (((kk * 4 + lg) ^ kp) << 3)]);
#pragma unroll
      for (int mt = 0; mt < 6; ++mt)
        acc[mt][j] = __builtin_amdgcn_mfma_f32_16x16x32_bf16(a[mt][kk], bfrag, acc[mt][j], 0, 0, 0);
    }
  }

  __syncthreads();   // staging reads complete; reuse flds as [o][px'] u16

#pragma unroll
  for (int mt = 0; mt < 6; ++mt) {
#pragma unroll
    for (int r = 0; r < 4; ++r) {
      int o = mt * 16 + lg * 4 + r;          // (o>>2)&3 == lg
      float s = 0.f, q = 0.f;
#pragma unroll
      for (int j = 0; j < 4; ++j) {
        unsigned short h = f2bf(acc[mt][j][r]);
        float vv = bf2f(h);
        int px = (wv * 4 + j) * 16 + lm;
        flds[o * 256 + (px ^ (lg << 4))] = h;
        s += vv; q += vv * vv;
      }
      s += __shfl_xor(s, 1); q += __shfl_xor(q, 1);
      s += __shfl_xor(s, 2); q += __shfl_xor(q, 2);
      s += __shfl_xor(s, 4); q += __shfl_xor(q, 4);
      s += __shfl_xor(s, 8); q += __shfl_xor(q, 8);
      if (lm == 0) { atomicAdd(&lsum[o], s); atomicAdd(&lsq[o], q); }
    }
  }
  __syncthreads();

  unsigned short* mbase = mixed + (long)b * CC * HWn + p0;
  int o2 = tid >> 5;          // 0..7
  int pxg = tid & 31;         // 8-px group
#pragma unroll
  for (int i = 0; i < 12; ++i) {
    int o = i * 8 + o2;
    int key = (o >> 2) & 3;
    uint4 vv = *(const uint4*)(&flds[o * 256 + ((pxg * 8) ^ (key << 4))]);
    *(uint4*)(mbase + (long)o * HWn + pxg * 8) = vv;
  }

  if (tid < CC) atomicAdd(&ssum[tid], lsum[tid]);
  else if (tid < 2 * CC) atomicAdd(&ssq[tid - CC], lsq[tid - CC]);
}

// -------- BN (affine=False, inline finalize) + exact GELU, bf16->f32 --------
__global__ __launch_bounds__(256) void k_bngelu(const unsigned short* __restrict__ mixed,
                                                const float* __restrict__ ssum,
                                                const float* __restrict__ ssq,
                                                float* __restrict__ out) {
  long e = ((long)blockIdx.x * 256 + threadIdx.x) * 8;
  int o = (int)((e / HWn) % CC);       // 12544 % 8 == 0 -> same plane
  float m = ssum[o] * (1.0f / NPIX);
  float qm = ssq[o] * (1.0f / NPIX);
  float r = 1.0f / sqrtf(qm - m * m + EPSf);
  bf16x8 v = *(const bf16x8*)(mixed + e);
  float4 g0, g1;
  float z;
  z = (bf2f((unsigned short)v[0]) - m) * r; g0.x = 0.5f * z * (1.0f + erff(z * 0.70710678f));
  z = (bf2f((unsigned short)v[1]) - m) * r; g0.y = 0.5f * z * (1.0f + erff(z * 0.70710678f));
  z = (bf2f((unsigned short)v[2]) - m) * r; g0.z = 0.5f * z * (1.0f + erff(z * 0.70710678f));
  z = (bf2f((unsigned short)v[3]) - m) * r; g0.w = 0.5f * z * (1.0f + erff(z * 0.70710678f));
  z = (bf2f((unsigned short)v[4]) - m) * r; g1.x = 0.5f * z * (1.0f + erff(z * 0.70710678f));
  z = (bf2f((unsigned short)v[5]) - m) * r; g1.y = 0.5f * z * (1.0f + erff(z * 0.70710678f));
  z = (bf2f((unsigned short)v[6]) - m) * r; g1.z = 0.5f * z * (1.0f + erff(z * 0.70710678f));
  z = (bf2f((unsigned short)v[7]) - m) * r; g1.w = 0.5f * z * (1.0f + erff(z * 0.70710678f));
  *(float4*)(out + e)     = g0;
  *(float4*)(out + e + 4) = g1;
}

extern "C" void kernel_launch(void* const* d_in, const int* in_sizes, int n_in,
                              void* d_out, int out_size, void* d_ws, size_t ws_size,
                              hipStream_t stream) {
  const float* hk   = (const float*)d_in[0];   // local_hk [96,1,7,7]
  const float* x    = (const float*)d_in[1];   // x [32,96,112,112]
  const float* wmix = (const float*)d_in[2];   // w_mix [96,96]
  const float* bmix = (const float*)d_in[3];   // b_mix [96] (cancels in BN)
  (void)bmix;
  float* out = (float*)d_out;

  char* ws = (char*)d_ws;
  float* stats = (float*)ws;                           // sum[96], ssq[96]
  unsigned short* wbf     = (unsigned short*)(ws + 2048);            // 18432 B
  unsigned short* featbf  = (unsigned short*)(ws + 32768);           // 77,070,336 B
  unsigned short* mixedbf = (unsigned short*)(ws + 32768 + 77070336);

  hipMemsetAsync(stats, 0, 768, stream);       // zero sum+ssq each call

  k_prep<<<36, 256, 0, stream>>>(wmix, wbf);
  k_conv<<<3072, 512, 0, stream>>>(x, hk, featbf);
  k_mix<<<1568, 256, 0, stream>>>(featbf, wbf, mixedbf, stats, stats + 96);
  k_bngelu<<<18816, 256, 0, stream>>>(mixedbf, stats, stats + 96, out);
}